// Round 10
// baseline (76.149 us; speedup 1.0000x reference)
//
#include <hip/hip_runtime.h>
#include <hip/hip_bf16.h>
#include <math.h>

// WavefunctionEmbedding, two-kernel histogram+MFMA:
//   out[b,i,2k+0/1] = sum_j amp_ij * {cos,sin}(wn_k * r_ij)
// K1: per-4-row radial histograms (cubic Lagrange deposit, int32 fixed-point
//     LDS ds_add) -> H bf16 [BN x 288]; blocks 0..511 also emit W^T bf16
//     [512 x 288] (row c = cos/sin track of wn_{c/2} at nodes r=(k-1)h).
// K2: out = H x W^T^T via v_mfma_f32_16x16x32_bf16, register-only (no LDS),
//     9 K-frags prefetched; 6144 tiles, 6 waves/SIMD; inputs L2-resident.
//
// R10 rationale vs R9 (kernel ~30 us): the contraction is a 3072x512x288
// GEMM = ~0.3 us of MFMA pipe vs ~10-15 us of VALU. The harness's 42 us ws
// re-poison fill is stream-ordered ahead of us REGARDLESS of ws use (R8/R9
// evidence), so materializing H/W in ws costs nothing extra.
// bf16 quantization of H/W adds <= ~0.01 abs err (0.031 measured, 0.083 thr).

#define N_FIXED  1536
#define K_FIXED  256
#define QBINS    256
#define QG       260            // node k represents r = (k-1)*h
#define KDIM     288            // padded K (9 x 32); slots 260..287 stay zero
#define ROWS     4              // rows per hist block (768 blocks)
#define NTHREADS 512
#define FPSCALE  4194304.0f     // 2^22 fixed-point scale for hist deposits

typedef __attribute__((ext_vector_type(8))) short bf16x8;
typedef __attribute__((ext_vector_type(4))) float f32x4;

// ---------------- fallback: direct kernel (round-1, known-good) ------------
__global__ __launch_bounds__(256) void wf_direct_kernel(
    const float* __restrict__ coords, const unsigned char* __restrict__ mask,
    const float* __restrict__ wavenumbers, float* __restrict__ out, int N, int K)
{
    __shared__ float2 pairs[N_FIXED];
    const int row = blockIdx.x;
    const int b   = row / N;
    const int i   = row - b * N;
    const int t   = threadIdx.x;
    const float* crow = coords + (size_t)b * N * 3;
    const float xi = crow[i*3+0], yi = crow[i*3+1], zi = crow[i*3+2];
    const unsigned char* mrow = mask + (size_t)b * N;
    for (int j = t; j < N; j += blockDim.x) {
        float dx = crow[j*3+0]-xi, dy = crow[j*3+1]-yi, dz = crow[j*3+2]-zi;
        float d2 = fmaf(dx,dx, fmaf(dy,dy, fmaf(dz,dz, 1e-12f)));
        float r  = sqrtf(d2);
        float amp = 0.07957747154594767f / fmaxf(r, 1e-6f);
        if (j == i || mrow[j]) amp = 0.0f;
        pairs[j] = make_float2(r, amp);
    }
    __syncthreads();
    const int k = t;
    const float f = wavenumbers[k] * 0.15915494309189535f;
    float re = 0.0f, im = 0.0f;
    #pragma unroll 4
    for (int j = 0; j < N; ++j) {
        float2 p = pairs[j];
        float x  = __builtin_amdgcn_fractf(p.x * f);
        float c  = __builtin_amdgcn_cosf(x);
        float s  = __builtin_amdgcn_sinf(x);
        re = fmaf(c, p.y, re);
        im = fmaf(s, p.y, im);
    }
    float2* orow = (float2*)out + (size_t)row * K;
    orow[k] = make_float2(re, im);
}

// ---------------- K1: histograms -> H bf16, plus W^T bf16 ------------------
__global__ __launch_bounds__(NTHREADS) void wf_hist_kernel(
    const float* __restrict__ coords, const unsigned char* __restrict__ mask,
    const float* __restrict__ wavenumbers,
    __hip_bfloat16* __restrict__ Wt,       // [2K][KDIM]
    __hip_bfloat16* __restrict__ Hb,       // [BN][KDIM]
    int n_pts, int N)
{
    __shared__ int   hist[ROWS * KDIM];    // 4.5 KB, r-major, stride 288
    __shared__ float red[8];

    const int i0 = blockIdx.x * ROWS;      // first global row of this block
    const int b  = i0 / N;                 // N % ROWS == 0 -> block within b
    const int t  = threadIdx.x;

    // ---- GLOBAL rmax (identical reduction in every block -> shared h) ----
    float m = 0.0f;
    for (int p = t; p < n_pts; p += NTHREADS) {
        float x = coords[3*p], y = coords[3*p+1], z = coords[3*p+2];
        m = fmaxf(m, fmaf(x,x, fmaf(y,y, z*z)));
    }
    #pragma unroll
    for (int off = 32; off >= 1; off >>= 1)
        m = fmaxf(m, __shfl_down(m, off, 64));
    if ((t & 63) == 0) red[t >> 6] = m;
    for (int a = t; a < ROWS * KDIM; a += NTHREADS) hist[a] = 0;
    __syncthreads();
    float mm = red[0];
    #pragma unroll
    for (int w = 1; w < 8; ++w) mm = fmaxf(mm, red[w]);
    const float rmax = 2.0005f * sqrtf(mm) + 1e-3f;   // r_ij <= 2 max|c|
    const float h    = rmax / (float)QBINS;           // => u = r/h < 256
    const float inv_h = 1.0f / h;

    // ---- blocks 0..511: W^T row c = blockIdx: trig(wn_{c/2}, (k-1)h) ----
    if (blockIdx.x < 2 * K_FIXED && t < KDIM) {
        float v = 0.0f;
        if (t < QG) {
            const float rnode = ((float)t - 1.0f) * h;
            const float arg = __builtin_amdgcn_fractf(
                wavenumbers[blockIdx.x >> 1] * 0.15915494309189535f * rnode);
            v = (blockIdx.x & 1) ? __builtin_amdgcn_sinf(arg)
                                 : __builtin_amdgcn_cosf(arg);
        }
        Wt[(size_t)blockIdx.x * KDIM + t] = __float2bfloat16(v);
    }

    // ---- histograms: each j loaded once, deposit into all ROWS rows ----
    const float* crow = coords + (size_t)b * N * 3;
    const unsigned char* mrow = mask + (size_t)b * N;
    const int il0 = i0 - b * N;
    float cx[ROWS], cy[ROWS], cz[ROWS];
    #pragma unroll
    for (int r = 0; r < ROWS; ++r) {
        cx[r] = crow[3*(il0+r)];
        cy[r] = crow[3*(il0+r)+1];
        cz[r] = crow[3*(il0+r)+2];
    }

    #pragma unroll
    for (int s = 0; s < N_FIXED / NTHREADS; ++s) {
        const int j = t + NTHREADS * s;
        const float xj = crow[3*j], yj = crow[3*j+1], zj = crow[3*j+2];
        const bool masked = (mrow[j] != 0);
        #pragma unroll
        for (int r = 0; r < ROWS; ++r) {
            float dx = xj - cx[r];
            float dy = yj - cy[r];
            float dz = zj - cz[r];
            float d2 = fmaf(dx,dx, fmaf(dy,dy, fmaf(dz,dz, 1e-12f)));
            float rsq = __builtin_amdgcn_rsqf(d2);     // 1/r, r >= 1e-6
            float amp = 0.07957747154594767f * rsq;    // 1/(4 pi r)
            if (j == il0 + r || masked) amp = 0.0f;

            float u  = d2 * rsq * inv_h;               // r/h, in [0,256)
            float qf = floorf(u);
            int   q0 = (int)qf;                        // 0..255
            float tt = u - qf;
            // Lagrange cubic through nodes {-1,0,1,2} at offset tt
            float as6 = amp * (FPSCALE * (1.0f/6.0f));
            float as2 = amp * (FPSCALE * 0.5f);
            float tm1 = tt + 1.0f, t1 = tt - 1.0f, t2 = tt - 2.0f;
            float p  = tt  * t1;
            float qq = tm1 * t2;
            int w0 = (int)(-(p  * t2)  * as6);
            int w1 = (int)( (qq * t1)  * as2);
            int w2 = (int)(-(qq * tt)  * as2);
            int w3 = (int)( (p  * tm1) * as6);
            int* hb = &hist[r * KDIM + q0];
            atomicAdd(hb + 0, w0);                     // native ds_add
            atomicAdd(hb + 1, w1);
            atomicAdd(hb + 2, w2);
            atomicAdd(hb + 3, w3);
        }
    }
    __syncthreads();

    // ---- writeback: H rows as bf16 (slots 259..287 are zero padding) ----
    __hip_bfloat16* Hrow = Hb + (size_t)i0 * KDIM;
    const float invS = 1.0f / FPSCALE;
    for (int a = t; a < ROWS * KDIM; a += NTHREADS)
        Hrow[a] = __float2bfloat16((float)hist[a] * invS);
}

// ---------------- K2: out = H x W via MFMA, register-only ------------------
__global__ __launch_bounds__(256) void wf_gemm_kernel(
    const __hip_bfloat16* __restrict__ Hb,   // [BN][KDIM]
    const __hip_bfloat16* __restrict__ Wt,   // [2K][KDIM]
    float* __restrict__ out)                 // [BN][2K]
{
    const int wave = threadIdx.x >> 6;
    const int lane = threadIdx.x & 63;
    const int tile = blockIdx.x * 4 + wave;        // 6144 tiles
    const int mt   = tile >> 5;                    // 192 m-tiles
    const int nt   = tile & 31;                    // 32 n-tiles
    const int m0   = mt * 16, n0 = nt * 16;
    const int quad = lane >> 4, idx = lane & 15;

    // A-frag: lane holds A[m=idx][k=quad*8+j]; B-frag: B[k=quad*8+j][n=idx]
    const short* Arow = (const short*)Hb + (size_t)(m0 + idx) * KDIM + quad * 8;
    const short* Brow = (const short*)Wt + (size_t)(n0 + idx) * KDIM + quad * 8;

    bf16x8 a[9], bfr[9];
    #pragma unroll
    for (int kk = 0; kk < 9; ++kk) {
        a[kk]   = *(const bf16x8*)(Arow + kk * 32);  // global_load_dwordx4
        bfr[kk] = *(const bf16x8*)(Brow + kk * 32);
    }
    f32x4 acc = {0.0f, 0.0f, 0.0f, 0.0f};
    #pragma unroll
    for (int kk = 0; kk < 9; ++kk)
        acc = __builtin_amdgcn_mfma_f32_16x16x32_bf16(a[kk], bfr[kk], acc, 0, 0, 0);

    // C/D: col = idx, row = quad*4 + reg
    float* orow = out + (size_t)(m0 + quad * 4) * (2 * K_FIXED) + n0 + idx;
    #pragma unroll
    for (int r = 0; r < 4; ++r)
        orow[(size_t)r * (2 * K_FIXED)] = acc[r];
}

extern "C" void kernel_launch(void* const* d_in, const int* in_sizes, int n_in,
                              void* d_out, int out_size, void* d_ws, size_t ws_size,
                              hipStream_t stream) {
    const float* coords          = (const float*)d_in[0];
    const unsigned char* mask    = (const unsigned char*)d_in[1];
    const float* wavenumbers     = (const float*)d_in[2];
    float* out                   = (float*)d_out;

    const int K  = in_sizes[2];
    const int BN = in_sizes[0] / 3;        // B*N
    const int N  = N_FIXED;

    // ws layout (bytes): Wt [512*288 bf16] | Hb [BN*288 bf16]
    const size_t Wt_bytes = (size_t)(2 * K_FIXED) * KDIM * sizeof(__hip_bfloat16);
    const size_t need     = Wt_bytes + (size_t)BN * KDIM * sizeof(__hip_bfloat16);

    if (K != K_FIXED || BN % N != 0 || (N % ROWS) != 0 ||
        (N % NTHREADS) != 0 || (BN % 16) != 0 ||
        (BN / ROWS) < 2 * K_FIXED || ws_size < need) {
        wf_direct_kernel<<<BN, K, 0, stream>>>(coords, mask, wavenumbers, out, N, K);
        return;
    }

    __hip_bfloat16* Wt = (__hip_bfloat16*)d_ws;
    __hip_bfloat16* Hb = Wt + (size_t)(2 * K_FIXED) * KDIM;

    wf_hist_kernel<<<BN / ROWS, NTHREADS, 0, stream>>>(coords, mask,
                                                       wavenumbers, Wt, Hb, BN, N);
    const int tiles = (BN / 16) * (2 * K_FIXED / 16);   // 6144
    wf_gemm_kernel<<<tiles / 4, 256, 0, stream>>>(Hb, Wt, out);
}